// Round 1
// 528.945 us; speedup vs baseline: 1.0036x; 1.0036x over previous
//
#include <hip/hip_runtime.h>
#include <math.h>

// Problem constants
constexpr int cB   = 2;
constexpr int cS   = 2048;
constexpr int cHID = 2048;
constexpr int cNH  = 16;
constexpr int cNKV = 8;
constexpr int cHD  = 128;
constexpr int cQKV = 4112;           // NH*HD + NH + 2*NKV*HD
constexpr int cM   = cB * cS;        // 4096
constexpr int cK   = 2048;           // GEMM K (both GEMMs)

// REORDERED qkv layout (vs reference): [Q 0..2048)[K 2048..3072)[V 3072..4096)[gate 4096..4112)
// This makes GEMM1's MFMA-covered width exactly 4096 = 16 x 256 tiles (zero-tail
// grid of 256 blocks at 1 block/CU); the 16 gate columns are a separate fp32 GEMV.
constexpr int cKO2 = 2048;
constexpr int cVO2 = 3072;
constexpr int cGO2 = 4096;

typedef short v8s __attribute__((ext_vector_type(8)));
typedef _Float16 v8h __attribute__((ext_vector_type(8)));
typedef float v4f __attribute__((ext_vector_type(4)));

static __device__ __forceinline__ unsigned short f2h(float f) {
    return __builtin_bit_cast(unsigned short, (_Float16)f);
}
// fp16 hi/lo split: x ~= hi + lo with |residual| ~ 2^-22 |x|
static __device__ __forceinline__ void split2h(float f, unsigned short& hi, unsigned short& lo) {
    _Float16 h = (_Float16)f;
    hi = __builtin_bit_cast(unsigned short, h);
    lo = __builtin_bit_cast(unsigned short, (_Float16)(f - (float)h));
}

#define GLD16(gp, lp)                                                          \
    __builtin_amdgcn_global_load_lds(                                          \
        (const __attribute__((address_space(1))) void*)(gp),                   \
        (__attribute__((address_space(3))) void*)(lp), 16, 0, 0)

template<int N> static __device__ __forceinline__ void vmwait() {
    asm volatile("s_waitcnt vmcnt(%0)" :: "n"(N) : "memory");
}
static __device__ __forceinline__ void lgkm0() {
    asm volatile("s_waitcnt lgkmcnt(0)" ::: "memory");
    __builtin_amdgcn_sched_barrier(0);
}
static __device__ __forceinline__ void barrier_() {
    __builtin_amdgcn_sched_barrier(0);
    __builtin_amdgcn_s_barrier();
    __builtin_amdgcn_sched_barrier(0);
}

// ---------------------------------------------------------------------------
// Split fp32 [rows][2048] into planar fp16 hi/lo (A-operands).
// ---------------------------------------------------------------------------
__global__ __launch_bounds__(256) void split_mat2(const float* __restrict__ X,
                                                  unsigned short* __restrict__ H,
                                                  unsigned short* __restrict__ L,
                                                  int rows)
{
    int idx = blockIdx.x * 256 + threadIdx.x;    // one float4 per thread
    int c4 = idx & 511;
    int r  = idx >> 9;
    float4 v = make_float4(0.f, 0.f, 0.f, 0.f);
    if (r < rows) v = *(const float4*)&X[(size_t)r * cK + c4 * 4];
    ushort4 h, l;
    split2h(v.x, h.x, l.x); split2h(v.y, h.y, l.y);
    split2h(v.z, h.z, l.z); split2h(v.w, h.w, l.w);
    size_t o = (size_t)r * cK + c4 * 4;
    *(ushort4*)&H[o] = h;
    *(ushort4*)&L[o] = l;
}

// ---------------------------------------------------------------------------
// fp16 hi-only convert (B-operand, w_o): [rows][2048]
// ---------------------------------------------------------------------------
__global__ __launch_bounds__(256) void split_math(const float* __restrict__ X,
                                                  unsigned short* __restrict__ H,
                                                  int rows)
{
    int idx = blockIdx.x * 256 + threadIdx.x;
    int c4 = idx & 511;
    int r  = idx >> 9;
    float4 v = make_float4(0.f, 0.f, 0.f, 0.f);
    if (r < rows) v = *(const float4*)&X[(size_t)r * cK + c4 * 4];
    *(ushort4*)&H[(size_t)r * cK + c4 * 4] =
        make_ushort4(f2h(v.x), f2h(v.y), f2h(v.z), f2h(v.w));
}

// ---------------------------------------------------------------------------
// w_qkv -> fp16 hi, gate rows skipped: Bh row n = w_qkv row (n<2048 ? n : n+16)
// 4096 output rows exactly.
// ---------------------------------------------------------------------------
__global__ __launch_bounds__(256) void split_maqkv(const float* __restrict__ X,
                                                   unsigned short* __restrict__ H)
{
    int idx = blockIdx.x * 256 + threadIdx.x;
    int c4 = idx & 511;
    int r  = idx >> 9;                       // 0..4095
    int src = r + (r >= cHID ? 16 : 0);      // skip the 16 gate rows
    float4 v = *(const float4*)&X[(size_t)src * cK + c4 * 4];
    *(ushort4*)&H[(size_t)r * cK + c4 * 4] =
        make_ushort4(f2h(v.x), f2h(v.y), f2h(v.z), f2h(v.w));
}

// ---------------------------------------------------------------------------
// C[M,BNtiles*BN] = ((Ah+Al) @ Bh^T) * outScale  -- fp16 split, folded as a
// K'=4096 GEMM where k'-tile t uses plane (t&1 ? Al : Ah) vs Bh chunk (t>>1).
// 256xBN tile, 8 waves, 4 K'-tile LDS buffers, counted-vmcnt deep pipeline
// (prefetch 3 tiles ahead; vmcnt never drained to 0 in the main loop),
// 2 phases per tile with setprio(1) around each MFMA cluster.
// MF = m-frags/wave, NF = n-frags/wave. <8,4>: BN=256 (GEMM1, 128KB LDS).
// <4,4>: BN=128 (GEMM2, 96KB LDS). Both launch 1 block/CU, zero-tail grids.
// XOR chunk-swizzled staging (same measured-0-conflict pattern as before).
// ---------------------------------------------------------------------------
template<int MF, int NF>
__global__ __launch_bounds__(512, 2) void gemm8p(const unsigned short* __restrict__ Ah,
                                                 const unsigned short* __restrict__ Al,
                                                 const unsigned short* __restrict__ Bh,
                                                 float* __restrict__ C, int ldc,
                                                 float outScale, int nxt)
{
    constexpr int NWM = 16 / MF;               // waves along M (BM = 256 always)
    constexpr int BN  = 16 * NF * (8 / NWM);   // 256 or 128
    constexpr int BSZ = BN * 32;               // B-tile shorts per buffer
    constexpr int LB  = BN / 128;              // B gld_lds per thread per tile
    constexpr int L   = 2 + LB;                // total gld_lds per thread per tile
    constexpr int NT  = 2 * (cK / 32);         // 128 folded k'-tiles

    __shared__ __align__(16) unsigned short sA[4 * 8192];
    __shared__ __align__(16) unsigned short sB[4 * BSZ];

    const int tid = threadIdx.x;
    const int lane = tid & 63, w = tid >> 6;
    const int rl = lane & 15, quad = lane >> 4;
    const int wm = (w % NWM) * 16 * MF;
    const int wn = (w / NWM) * 16 * NF;

    // bijective XCD swizzle (grid is a multiple of 8): consecutive wg share A-panel
    const int nwg = gridDim.x;
    const int qx = nwg >> 3;
    const int wg = (blockIdx.x & 7) * qx + (blockIdx.x >> 3);
    const int bm = (wg / nxt) * 256;
    const int bn = (wg % nxt) * BN;

    // staging: inst j of wave w stages 16-row group; XOR-swizzled 16B chunks
    const int srow = lane >> 2;
    const int gc = ((lane & 3) ^ ((lane >> 3) & 3)) * 8;
    const int fc = (quad ^ ((rl >> 1) & 3)) * 8;     // frag-read swizzle inverse

    const size_t aOff = (size_t)(bm + 2 * w * 16 + srow) * cK + gc;
    const size_t bOff = (size_t)(bn + (LB == 2 ? 2 * w : w) * 16 + srow) * cK + gc;
    unsigned short* dA0 = sA + 2 * w * 512;
    unsigned short* dA1 = sA + (2 * w + 1) * 512;
    unsigned short* dB0 = sB + (LB == 2 ? 2 * w : w) * 512;
    unsigned short* dB1 = sB + ((LB == 2 ? 2 * w + 1 : 0)) * 512;

    v4f acc[MF][NF];
#pragma unroll
    for (int i = 0; i < MF; ++i)
#pragma unroll
        for (int j = 0; j < NF; ++j) acc[i][j] = (v4f){0.f, 0.f, 0.f, 0.f};

    auto stageA = [&](int t, int buf) {
        const unsigned short* pl = (t & 1) ? Al : Ah;
        const size_t ko = (size_t)(t >> 1) * 32;
        GLD16(pl + aOff + ko, dA0 + buf * 8192);
        GLD16(pl + aOff + 16 * cK + ko, dA1 + buf * 8192);
    };
    auto stageB = [&](int t, int buf) {
        const size_t ko = (size_t)(t >> 1) * 32;
        GLD16(Bh + bOff + ko, dB0 + buf * BSZ);
        if (LB == 2) GLD16(Bh + bOff + 16 * cK + ko, dB1 + buf * BSZ);
    };

    // prologue: 3 tiles in flight (per-tile issue order is always A then B)
    stageA(0, 0); stageB(0, 0);
    stageA(1, 1); stageB(1, 1);
    stageA(2, 2); stageB(2, 2);

    for (int t = 0; t < NT; ++t) {
        // counted wait: retire exactly tile t's loads; keep t+1, t+2 in flight
        if (t < NT - 2)       vmwait<2 * L>();
        else if (t == NT - 2) vmwait<L>();
        else                  vmwait<0>();
        barrier_();                               // tile t globally visible

        const int cur = t & 3;
        const unsigned short* bufA = sA + cur * 8192;
        const unsigned short* bufB = sB + cur * BSZ;

        // ---- phase 0: A-frags + first half of B-frags, stage A of t+3 ----
        v8h af[MF], bf[NF / 2];
#pragma unroll
        for (int i = 0; i < MF; ++i)
            af[i] = *(const v8h*)&bufA[(wm + 16 * i + rl) * 32 + fc];
#pragma unroll
        for (int j = 0; j < NF / 2; ++j)
            bf[j] = *(const v8h*)&bufB[(wn + 16 * j + rl) * 32 + fc];
        if (t + 3 < NT) stageA(t + 3, (t + 3) & 3);
        lgkm0();
        __builtin_amdgcn_s_setprio(1);
#pragma unroll
        for (int i = 0; i < MF; ++i)
#pragma unroll
            for (int j = 0; j < NF / 2; ++j)
                acc[i][j] = __builtin_amdgcn_mfma_f32_16x16x32_f16(af[i], bf[j], acc[i][j], 0, 0, 0);
        __builtin_amdgcn_s_setprio(0);
        barrier_();

        // ---- phase 1: second half of B-frags, stage B of t+3 ----
        v8h bg[NF / 2];
#pragma unroll
        for (int j = 0; j < NF / 2; ++j)
            bg[j] = *(const v8h*)&bufB[(wn + 16 * (NF / 2 + j) + rl) * 32 + fc];
        if (t + 3 < NT) stageB(t + 3, (t + 3) & 3);
        lgkm0();
        __builtin_amdgcn_s_setprio(1);
#pragma unroll
        for (int i = 0; i < MF; ++i)
#pragma unroll
            for (int j = 0; j < NF / 2; ++j)
                acc[i][NF / 2 + j] = __builtin_amdgcn_mfma_f32_16x16x32_f16(af[i], bg[j], acc[i][NF / 2 + j], 0, 0, 0);
        __builtin_amdgcn_s_setprio(0);
        // no barrier here: loop-top vmcnt+barrier provides the ordering
    }

    // epilogue
#pragma unroll
    for (int i = 0; i < MF; ++i)
#pragma unroll
        for (int j = 0; j < NF; ++j) {
            const int col = bn + wn + 16 * j + rl;
            const int row0 = bm + wm + 16 * i + quad * 4;
#pragma unroll
            for (int r = 0; r < 4; ++r)
                C[(size_t)(row0 + r) * ldc + col] = acc[i][j][r] * outScale;
        }
}

// ---------------------------------------------------------------------------
// Gate GEMV (fp32, exact): qkv[m][4096+g] = hidden[m] . w_qkv[2048+g]
// One wave per hidden row; 16 gate rows are L2-hot across all blocks.
// ---------------------------------------------------------------------------
__global__ __launch_bounds__(256) void gate_kernel(const float* __restrict__ hidden,
                                                   const float* __restrict__ w_qkv,
                                                   float* __restrict__ qkv)
{
    const int lane = threadIdx.x & 63, wv = threadIdx.x >> 6;
    const int m = blockIdx.x * 4 + wv;
    const float* hp = hidden + (size_t)m * cK;
    float4 h4[8];
#pragma unroll
    for (int i = 0; i < 8; ++i) h4[i] = *(const float4*)&hp[i * 256 + lane * 4];
#pragma unroll 1
    for (int g = 0; g < 16; ++g) {
        const float* wp = w_qkv + (size_t)(cHID + g) * cK;
        float acc = 0.f;
#pragma unroll
        for (int i = 0; i < 8; ++i) {
            float4 w4 = *(const float4*)&wp[i * 256 + lane * 4];
            acc = fmaf(h4[i].x, w4.x, acc);
            acc = fmaf(h4[i].y, w4.y, acc);
            acc = fmaf(h4[i].z, w4.z, acc);
            acc = fmaf(h4[i].w, w4.w, acc);
        }
#pragma unroll
        for (int k = 1; k < 64; k <<= 1) acc += __shfl_xor(acc, k);
        if (lane == 0) qkv[(size_t)m * cQKV + cGO2 + g] = acc;
    }
}

// ---------------------------------------------------------------------------
// In-place RoPE on q and k regions of qkv (M, 4112). New layout: K at 2048.
// ---------------------------------------------------------------------------
__global__ __launch_bounds__(256) void rope_kernel(float* __restrict__ qkv,
                                                   const float* __restrict__ cosp,
                                                   const float* __restrict__ sinp)
{
    int idx = blockIdx.x * 256 + threadIdx.x;
    const int qcount = cM * cNH * (cHD / 2);
    int d, m;
    size_t base;
    if (idx < qcount) {
        d = idx & 63;
        int t = idx >> 6;
        int head = t & (cNH - 1);
        m = t >> 4;
        base = (size_t)m * cQKV + head * cHD;
    } else {
        int loc = idx - qcount;
        d = loc & 63;
        int t = loc >> 6;
        int head = t & (cNKV - 1);
        m = t >> 3;
        base = (size_t)m * cQKV + cKO2 + head * cHD;
    }
    int s = m & (cS - 1);
    float x1 = qkv[base + d], x2 = qkv[base + d + 64];
    float c1 = cosp[s * cHD + d], c2 = cosp[s * cHD + d + 64];
    float s1 = sinp[s * cHD + d], s2 = sinp[s * cHD + d + 64];
    qkv[base + d]      = x1 * c1 - x2 * s1;
    qkv[base + d + 64] = x2 * c2 + x1 * s2;
}

// ---------------------------------------------------------------------------
// Roped K -> planar fp16 (hi only): Kh[b][kvh][s][128]
// ---------------------------------------------------------------------------
__global__ __launch_bounds__(256) void split_k_kernel(const float* __restrict__ qkv,
                                                      unsigned short* __restrict__ Kh)
{
    int idx = blockIdx.x * 256 + threadIdx.x;     // 2^20 float4 groups
    int d4 = idx & 31;
    int s  = (idx >> 5) & 2047;
    int kv = (idx >> 16) & 7;
    int b  = idx >> 19;
    const float4 v = *(const float4*)&qkv[(size_t)(b * cS + s) * cQKV + cKO2 + kv * cHD + d4 * 4];
    size_t o = ((size_t)((b * cNKV + kv) * cS + s)) * cHD + d4 * 4;
    *(ushort4*)&Kh[o] = make_ushort4(f2h(v.x), f2h(v.y), f2h(v.z), f2h(v.w));
}

// ---------------------------------------------------------------------------
// V, transposed, fp16 hi only: Vh[b][kvh][d][s]
// ---------------------------------------------------------------------------
__global__ __launch_bounds__(256) void split_vt_kernel(const float* __restrict__ qkv,
                                                       unsigned short* __restrict__ Vh)
{
    __shared__ float T[128 * 132];
    const int t = threadIdx.x;
    const int tile = blockIdx.x, kv = blockIdx.y, b = blockIdx.z;
#pragma unroll
    for (int i = 0; i < 16; ++i) {
        int e = i * 256 + t;
        int row = e >> 5, c4 = e & 31;
        *(float4*)&T[row * 132 + c4 * 4] =
            *(const float4*)&qkv[(size_t)(b * cS + tile * 128 + row) * cQKV + cVO2 + kv * cHD + c4 * 4];
    }
    __syncthreads();
    const int d = t >> 1, half = t & 1;
    size_t ob = ((size_t)((b * cNKV + kv) * cHD + d)) * cS + tile * 128 + half * 64;
#pragma unroll
    for (int i = 0; i < 8; ++i) {
        unsigned short hh[8];
#pragma unroll
        for (int j = 0; j < 8; ++j)
            hh[j] = f2h(T[(half * 64 + i * 8 + j) * 132 + d]);
        *(ushort4*)&Vh[ob + i * 8]     = make_ushort4(hh[0], hh[1], hh[2], hh[3]);
        *(ushort4*)&Vh[ob + i * 8 + 4] = make_ushort4(hh[4], hh[5], hh[6], hh[7]);
    }
}

// ---------------------------------------------------------------------------
// MFMA flash attention + gate, S^T formulation, fp16, dbuf KV prefetch,
// FIXED-OFFSET softmax: p = exp2(S*sc - 10). (unchanged except gate offset)
// ---------------------------------------------------------------------------
__global__ __launch_bounds__(256, 2) void attn_mfma(const float* __restrict__ qkv,
                                                    const unsigned short* __restrict__ Kh,
                                                    const unsigned short* __restrict__ Vh,
                                                    unsigned short* __restrict__ Oh,
                                                    unsigned short* __restrict__ Ol)
{
    __shared__ __align__(16) unsigned short sKh[2 * 4096];
    __shared__ __align__(16) unsigned short sVh[2 * 4096];

    const int tid = threadIdx.x;
    const int lane = tid & 63, w = tid >> 6;
    const int rl = lane & 15, quad = lane >> 4;
    const int qt = blockIdx.x, h = blockIdx.y, b = blockIdx.z;
    const int kvh = h >> 1;
    const float sc = 0.08838834764831845f * 1.4426950408889634f;  // /sqrt(128)*log2e

    // ---- Q fragments, fp16 hi/lo, unscaled ----
    v8h Qh[2][4], Ql[2][4];
#pragma unroll
    for (int mt = 0; mt < 2; ++mt) {
        const float* qp0 = &qkv[(size_t)(b * cS + qt * 128 + w * 32 + mt * 16 + rl) * cQKV
                                + h * cHD + quad * 8];
#pragma unroll
        for (int c = 0; c < 4; ++c) {
            float4 x0 = *(const float4*)(qp0 + c * 32);
            float4 x1 = *(const float4*)(qp0 + c * 32 + 4);
            float f[8] = {x0.x, x0.y, x0.z, x0.w, x1.x, x1.y, x1.z, x1.w};
            v8s qh, ql;
#pragma unroll
            for (int j = 0; j < 8; ++j) {
                unsigned short hh, ll;
                split2h(f[j], hh, ll);
                qh[j] = (short)hh; ql[j] = (short)ll;
            }
            Qh[mt][c] = __builtin_bit_cast(v8h, qh);
            Ql[mt][c] = __builtin_bit_cast(v8h, ql);
        }
    }

    float l_i[2] = {0.f, 0.f};     // per-lane partial (this quad's k-rows)
    v4f O[2][8];   // O^T: [mt][dt], row d = dt*16+quad*4+r, col q = rl
#pragma unroll
    for (int mt = 0; mt < 2; ++mt)
#pragma unroll
        for (int dt = 0; dt < 8; ++dt) O[mt][dt] = (v4f){0.f, 0.f, 0.f, 0.f};

    const size_t kbase = ((size_t)((b * cNKV + kvh) * cS)) * cHD;
    const size_t vbase = ((size_t)((b * cNKV + kvh) * cHD)) * cS;

    // ---- staging pointers (GLD16: wave-uniform LDS base + lane*16B) ----
    const int kchunk = 4 * w + (lane >> 5);          // +2 for second inst
    const int krow = lane & 31;
    const unsigned short* gKh0 = Kh + kbase + (size_t)krow * cHD + kchunk * 8;
    const unsigned short* gVh0 = Vh + vbase + (size_t)lane * cS + w * 8;
    unsigned short* dKh0 = sKh + w * 1024;
    unsigned short* dVh0 = sVh + w * 1024;

#define STAGE(kt_, buf_)                                                         \
    do {                                                                         \
        const size_t ko_ = (size_t)(kt_) * (32 * cHD);                           \
        const size_t vo_ = (size_t)(kt_) * 32;                                   \
        const int bo_ = (buf_) * 4096;                                           \
        GLD16(gKh0 + ko_, dKh0 + bo_); GLD16(gKh0 + ko_ + 16, dKh0 + bo_ + 512); \
        GLD16(gVh0 + vo_, dVh0 + bo_);                                           \
        GLD16(gVh0 + vo_ + 64 * (size_t)cS, dVh0 + bo_ + 512);                   \
    } while (0)

    STAGE(0, 0);
    __syncthreads();

    for (int kt = 0; kt < cS / 32; ++kt) {
        const int cur = kt & 1;
        const int cbo = cur * 4096;

        // (1) hoist K fragments LDS -> registers (before prefetch)
        v8h kf[4][2];
#pragma unroll
        for (int c = 0; c < 4; ++c)
#pragma unroll
            for (int nt = 0; nt < 2; ++nt)
                kf[c][nt] = *(const v8h*)&sKh[cbo + ((4 * c + quad) * 32 + nt * 16 + rl) * 8];

        // (2) prefetch next tile
        if (kt < cS / 32 - 1) STAGE(kt + 1, cur ^ 1);

        // (3) S^T = K @ Q^T  (fp16 2-pass)
        v4f S[2][2];
#pragma unroll
        for (int mt = 0; mt < 2; ++mt)
#pragma unroll
            for (int nt = 0; nt < 2; ++nt) S[mt][nt] = (v4f){0.f, 0.f, 0.f, 0.f};
#pragma unroll
        for (int c = 0; c < 4; ++c)
#pragma unroll
            for (int nt = 0; nt < 2; ++nt)
#pragma unroll
                for (int mt = 0; mt < 2; ++mt) {
                    S[mt][nt] = __builtin_amdgcn_mfma_f32_16x16x32_f16(kf[c][nt], Qh[mt][c], S[mt][nt], 0, 0, 0);
                    S[mt][nt] = __builtin_amdgcn_mfma_f32_16x16x32_f16(kf[c][nt], Ql[mt][c], S[mt][nt], 0, 0, 0);
                }

        // (4) fixed-offset softmax: p = exp2(S*sc - 10); l partial accum;
        //     P^T fp16 B-frag via cvt_pkrtz + one shfl per jj
        v8h PhB[2];
#pragma unroll
        for (int mt = 0; mt < 2; ++mt) {
            float p[8];
#pragma unroll
            for (int nt = 0; nt < 2; ++nt)
#pragma unroll
                for (int r = 0; r < 4; ++r) {
                    float e = exp2f(fmaf(S[mt][nt][r], sc, -10.f));
                    p[nt * 4 + r] = e;
                    l_i[mt] += e;
                }
            // pk[r]: hi16 = h(p_nt0[r]), lo16 = h(p_nt1[r])
            int pk[4];
#pragma unroll
            for (int r = 0; r < 4; ++r)
                pk[r] = __builtin_bit_cast(int,
                        __builtin_amdgcn_cvt_pkrtz(p[4 + r], p[r]));
            // transpose C-layout -> B-frag (one shfl per jj)
            const int q2 = (quad & 1) * 2;
            const int hiHalf = quad >> 1;       // 0: nt0 (hi16), 1: nt1 (lo16)
            v8s ph;
#pragma unroll
            for (int jj = 0; jj < 8; ++jj) {
                int srcl = (q2 + (jj >> 2)) * 16 + rl;
                int v = __shfl(pk[jj & 3], srcl);
                ph[jj] = hiHalf ? (short)(v & 0xffff) : (short)(((unsigned)v) >> 16);
            }
            PhB[mt] = __builtin_bit_cast(v8h, ph);
        }

        // (5) O^T += V^T @ P^T  (fp16 1-pass)
#pragma unroll
        for (int dt = 0; dt < 8; ++dt) {
            v8h vh = *(const v8h*)&sVh[cbo + (quad * 128 + dt * 16 + rl) * 8];
#pragma unroll
            for (int mt = 0; mt < 2; ++mt)
                O[mt][dt] = __builtin_amdgcn_mfma_f32_16x16x32_f16(vh, PhB[mt], O[mt][dt], 0, 0, 0);
        }
        __syncthreads();
    }
#undef STAGE

    // ---- epilogue: reduce l across quads, x16/l, sigmoid gate, store ----
#pragma unroll
    for (int mt = 0; mt < 2; ++mt) {
        float lt = l_i[mt];
        lt += __shfl_xor(lt, 16);
        lt += __shfl_xor(lt, 32);
        int grow = b * cS + qt * 128 + w * 32 + mt * 16 + rl;
        float g = qkv[(size_t)grow * cQKV + cGO2 + h];
        float u = 16.f / ((1.f + __expf(-g)) * lt);
        size_t obase = (size_t)grow * cHID + h * cHD + quad * 4;
#pragma unroll
        for (int dt = 0; dt < 8; ++dt) {
            unsigned short hh[4], ll[4];
#pragma unroll
            for (int r = 0; r < 4; ++r) split2h(O[mt][dt][r] * u, hh[r], ll[r]);
            *(ushort4*)&Oh[obase + dt * 16] = make_ushort4(hh[0], hh[1], hh[2], hh[3]);
            *(ushort4*)&Ol[obase + dt * 16] = make_ushort4(ll[0], ll[1], ll[2], ll[3]);
        }
    }
}

// ---------------------------------------------------------------------------
extern "C" void kernel_launch(void* const* d_in, const int* in_sizes, int n_in,
                              void* d_out, int out_size, void* d_ws, size_t ws_size,
                              hipStream_t stream)
{
    (void)in_sizes; (void)n_in; (void)out_size; (void)ws_size;
    const float* hidden = (const float*)d_in[0];
    const float* cosp   = (const float*)d_in[1];
    const float* sinp   = (const float*)d_in[2];
    const float* w_qkv  = (const float*)d_in[3];
    const float* w_o    = (const float*)d_in[4];
    float* out = (float*)d_out;

    // Workspace layout (bytes):
    //  [0, 67371008)              qkv f32 [4096][4112] (REORDERED: Q|K|V|gate)
    //  [67371008, 101974016)      Bh (w_qkv hi, 4096x2048 fp16 = 16.8MB)
    //                             -> reused as Oh/Ol (attn out x16 hi/lo, 33.6MB)
    //  [101974016, 118751232)     Kh + Vh (fp16, 8.4MB each) -> later Wh (w_o hi)
    // d_out doubles as Ah/Al (hidden split) until GEMM2 writes it.
    char* ws = (char*)d_ws;
    float* qkv = (float*)ws;
    unsigned short* Bh = (unsigned short*)(ws + 67371008);
    unsigned short* Kh = (unsigned short*)(ws + 101974016);
    const size_t kvPlane = (size_t)cB * cNKV * cS * cHD;       // 4,194,304 elems
    unsigned short* Vh = Kh + kvPlane;

    unsigned short* Ahid = (unsigned short*)d_out;             // hidden split hi
    unsigned short* Alid = Ahid + (size_t)cM * cK;             // hidden split lo
    unsigned short* Oh = Bh;                                   // attn out hi
    unsigned short* Ol = Bh + (size_t)cM * cHID;               // attn out lo
    unsigned short* Wh = Kh;                                   // w_o hi

    // 1) split inputs to fp16
    split_mat2<<<dim3(cM * (cK / 4) / 256), 256, 0, stream>>>(hidden, Ahid, Alid, cM);
    split_maqkv<<<dim3(4096 * (cK / 4) / 256), 256, 0, stream>>>(w_qkv, Bh);

    // 2) QKV projection (Q|K|V, 4096 cols): deep-pipeline fp16-split GEMM,
    //    grid 16x16 = 256 blocks = exactly 1/CU (zero tail)
    gemm8p<8, 4><<<dim3(256), 512, 0, stream>>>(Ahid, Alid, Bh, qkv, cQKV, 1.0f, 16);

    // 2b) gate columns (16) in exact fp32
    gate_kernel<<<dim3(cM / 4), 256, 0, stream>>>(hidden, w_qkv, qkv);

    // 3) RoPE in place
    {
        int total = cM * cNH * (cHD / 2) + cM * cNKV * (cHD / 2);
        rope_kernel<<<dim3(total / 256), 256, 0, stream>>>(qkv, cosp, sinp);
    }

    // 4) K (planar) and V (transposed) to fp16 hi
    split_k_kernel<<<dim3(4096), 256, 0, stream>>>(qkv, Kh);
    split_vt_kernel<<<dim3(cS / 128, cNKV, cB), 256, 0, stream>>>(qkv, Vh);

    // 5) MFMA attention + gate -> Oh/Ol (overwrites dead w_qkv split)
    attn_mfma<<<dim3(cS / 128, cNH, cB), 256, 0, stream>>>(qkv, Kh, Vh, Oh, Ol);

    // 6) w_o hi (overwrites dead K plane)
    split_math<<<dim3(cHID * (cK / 4) / 256), 256, 0, stream>>>(w_o, Wh, cHID);

    // 7) output projection: BN=128 variant, grid 16x16 = 256 blocks (zero tail)
    gemm8p<4, 4><<<dim3(256), 512, 0, stream>>>(Oh, Ol, Wh, out, cHID, 1.0f / 16.0f, 16);
}

// Round 2
// 527.092 us; speedup vs baseline: 1.0071x; 1.0035x over previous
//
#include <hip/hip_runtime.h>
#include <math.h>

// Problem constants
constexpr int cB   = 2;
constexpr int cS   = 2048;
constexpr int cHID = 2048;
constexpr int cNH  = 16;
constexpr int cNKV = 8;
constexpr int cHD  = 128;
constexpr int cQKV = 4112;           // NH*HD + NH + 2*NKV*HD
constexpr int cM   = cB * cS;        // 4096
constexpr int cK   = 2048;           // GEMM K (both GEMMs)

// REORDERED qkv layout (vs reference): [Q 0..2048)[K 2048..3072)[V 3072..4096)[gate 4096..4112)
constexpr int cKO2 = 2048;
constexpr int cVO2 = 3072;
constexpr int cGO2 = 4096;

typedef short v8s __attribute__((ext_vector_type(8)));
typedef _Float16 v8h __attribute__((ext_vector_type(8)));
typedef float v4f __attribute__((ext_vector_type(4)));

static __device__ __forceinline__ unsigned short f2h(float f) {
    return __builtin_bit_cast(unsigned short, (_Float16)f);
}
// fp16 hi/lo split: x ~= hi + lo with |residual| ~ 2^-22 |x|
static __device__ __forceinline__ void split2h(float f, unsigned short& hi, unsigned short& lo) {
    _Float16 h = (_Float16)f;
    hi = __builtin_bit_cast(unsigned short, h);
    lo = __builtin_bit_cast(unsigned short, (_Float16)(f - (float)h));
}

#define GLD16(gp, lp)                                                          \
    __builtin_amdgcn_global_load_lds(                                          \
        (const __attribute__((address_space(1))) void*)(gp),                   \
        (__attribute__((address_space(3))) void*)(lp), 16, 0, 0)

template<int N> static __device__ __forceinline__ void vmwait() {
    asm volatile("s_waitcnt vmcnt(%0)" :: "n"(N) : "memory");
}
static __device__ __forceinline__ void lgkm0() {
    asm volatile("s_waitcnt lgkmcnt(0)" ::: "memory");
    __builtin_amdgcn_sched_barrier(0);
}
static __device__ __forceinline__ void barrier_() {
    __builtin_amdgcn_sched_barrier(0);
    __builtin_amdgcn_s_barrier();
    __builtin_amdgcn_sched_barrier(0);
}

// ---------------------------------------------------------------------------
// Split fp32 [rows][2048] into planar fp16 hi/lo (A-operands).
// ---------------------------------------------------------------------------
__global__ __launch_bounds__(256) void split_mat2(const float* __restrict__ X,
                                                  unsigned short* __restrict__ H,
                                                  unsigned short* __restrict__ L,
                                                  int rows)
{
    int idx = blockIdx.x * 256 + threadIdx.x;    // one float4 per thread
    int c4 = idx & 511;
    int r  = idx >> 9;
    float4 v = make_float4(0.f, 0.f, 0.f, 0.f);
    if (r < rows) v = *(const float4*)&X[(size_t)r * cK + c4 * 4];
    ushort4 h, l;
    split2h(v.x, h.x, l.x); split2h(v.y, h.y, l.y);
    split2h(v.z, h.z, l.z); split2h(v.w, h.w, l.w);
    size_t o = (size_t)r * cK + c4 * 4;
    *(ushort4*)&H[o] = h;
    *(ushort4*)&L[o] = l;
}

// ---------------------------------------------------------------------------
// fp16 hi-only convert (B-operand, w_o): [rows][2048]
// ---------------------------------------------------------------------------
__global__ __launch_bounds__(256) void split_math(const float* __restrict__ X,
                                                  unsigned short* __restrict__ H,
                                                  int rows)
{
    int idx = blockIdx.x * 256 + threadIdx.x;
    int c4 = idx & 511;
    int r  = idx >> 9;
    float4 v = make_float4(0.f, 0.f, 0.f, 0.f);
    if (r < rows) v = *(const float4*)&X[(size_t)r * cK + c4 * 4];
    *(ushort4*)&H[(size_t)r * cK + c4 * 4] =
        make_ushort4(f2h(v.x), f2h(v.y), f2h(v.z), f2h(v.w));
}

// ---------------------------------------------------------------------------
// w_qkv -> fp16 hi, gate rows skipped: Bh row n = w_qkv row (n<2048 ? n : n+16)
// ---------------------------------------------------------------------------
__global__ __launch_bounds__(256) void split_maqkv(const float* __restrict__ X,
                                                   unsigned short* __restrict__ H)
{
    int idx = blockIdx.x * 256 + threadIdx.x;
    int c4 = idx & 511;
    int r  = idx >> 9;                       // 0..4095
    int src = r + (r >= cHID ? 16 : 0);      // skip the 16 gate rows
    float4 v = *(const float4*)&X[(size_t)src * cK + c4 * 4];
    *(ushort4*)&H[(size_t)r * cK + c4 * 4] =
        make_ushort4(f2h(v.x), f2h(v.y), f2h(v.z), f2h(v.w));
}

// ---------------------------------------------------------------------------
// C[M,BNtiles*BN] = ((Ah+Al) @ Bh^T) * outScale  -- fp16 split, folded as a
// K'=4096 GEMM. 256xBN tile, 8 waves, 4 K'-tile LDS buffers, counted-vmcnt
// deep pipeline, 2 phases/tile with setprio around MFMA clusters.
// ---------------------------------------------------------------------------
template<int MF, int NF>
__global__ __launch_bounds__(512, 2) void gemm8p(const unsigned short* __restrict__ Ah,
                                                 const unsigned short* __restrict__ Al,
                                                 const unsigned short* __restrict__ Bh,
                                                 float* __restrict__ C, int ldc,
                                                 float outScale, int nxt)
{
    constexpr int NWM = 16 / MF;               // waves along M (BM = 256 always)
    constexpr int BN  = 16 * NF * (8 / NWM);   // 256 or 128
    constexpr int BSZ = BN * 32;               // B-tile shorts per buffer
    constexpr int LB  = BN / 128;              // B gld_lds per thread per tile
    constexpr int L   = 2 + LB;                // total gld_lds per thread per tile
    constexpr int NT  = 2 * (cK / 32);         // 128 folded k'-tiles

    __shared__ __align__(16) unsigned short sA[4 * 8192];
    __shared__ __align__(16) unsigned short sB[4 * BSZ];

    const int tid = threadIdx.x;
    const int lane = tid & 63, w = tid >> 6;
    const int rl = lane & 15, quad = lane >> 4;
    const int wm = (w % NWM) * 16 * MF;
    const int wn = (w / NWM) * 16 * NF;

    // bijective XCD swizzle (grid is a multiple of 8)
    const int nwg = gridDim.x;
    const int qx = nwg >> 3;
    const int wg = (blockIdx.x & 7) * qx + (blockIdx.x >> 3);
    const int bm = (wg / nxt) * 256;
    const int bn = (wg % nxt) * BN;

    // staging: XOR-swizzled 16B chunks
    const int srow = lane >> 2;
    const int gc = ((lane & 3) ^ ((lane >> 3) & 3)) * 8;
    const int fc = (quad ^ ((rl >> 1) & 3)) * 8;     // frag-read swizzle inverse

    const size_t aOff = (size_t)(bm + 2 * w * 16 + srow) * cK + gc;
    const size_t bOff = (size_t)(bn + (LB == 2 ? 2 * w : w) * 16 + srow) * cK + gc;
    unsigned short* dA0 = sA + 2 * w * 512;
    unsigned short* dA1 = sA + (2 * w + 1) * 512;
    unsigned short* dB0 = sB + (LB == 2 ? 2 * w : w) * 512;
    unsigned short* dB1 = sB + ((LB == 2 ? 2 * w + 1 : 0)) * 512;

    v4f acc[MF][NF];
#pragma unroll
    for (int i = 0; i < MF; ++i)
#pragma unroll
        for (int j = 0; j < NF; ++j) acc[i][j] = (v4f){0.f, 0.f, 0.f, 0.f};

    auto stageA = [&](int t, int buf) {
        const unsigned short* pl = (t & 1) ? Al : Ah;
        const size_t ko = (size_t)(t >> 1) * 32;
        GLD16(pl + aOff + ko, dA0 + buf * 8192);
        GLD16(pl + aOff + 16 * cK + ko, dA1 + buf * 8192);
    };
    auto stageB = [&](int t, int buf) {
        const size_t ko = (size_t)(t >> 1) * 32;
        GLD16(Bh + bOff + ko, dB0 + buf * BSZ);
        if (LB == 2) GLD16(Bh + bOff + 16 * cK + ko, dB1 + buf * BSZ);
    };

    // prologue: 3 tiles in flight (per-tile issue order is always A then B)
    stageA(0, 0); stageB(0, 0);
    stageA(1, 1); stageB(1, 1);
    stageA(2, 2); stageB(2, 2);

    for (int t = 0; t < NT; ++t) {
        if (t < NT - 2)       vmwait<2 * L>();
        else if (t == NT - 2) vmwait<L>();
        else                  vmwait<0>();
        barrier_();                               // tile t globally visible

        const int cur = t & 3;
        const unsigned short* bufA = sA + cur * 8192;
        const unsigned short* bufB = sB + cur * BSZ;

        // ---- phase 0: A-frags + first half of B-frags, stage A of t+3 ----
        v8h af[MF], bf[NF / 2];
#pragma unroll
        for (int i = 0; i < MF; ++i)
            af[i] = *(const v8h*)&bufA[(wm + 16 * i + rl) * 32 + fc];
#pragma unroll
        for (int j = 0; j < NF / 2; ++j)
            bf[j] = *(const v8h*)&bufB[(wn + 16 * j + rl) * 32 + fc];
        if (t + 3 < NT) stageA(t + 3, (t + 3) & 3);
        lgkm0();
        __builtin_amdgcn_s_setprio(1);
#pragma unroll
        for (int i = 0; i < MF; ++i)
#pragma unroll
            for (int j = 0; j < NF / 2; ++j)
                acc[i][j] = __builtin_amdgcn_mfma_f32_16x16x32_f16(af[i], bf[j], acc[i][j], 0, 0, 0);
        __builtin_amdgcn_s_setprio(0);
        barrier_();

        // ---- phase 1: second half of B-frags, stage B of t+3 ----
        v8h bg[NF / 2];
#pragma unroll
        for (int j = 0; j < NF / 2; ++j)
            bg[j] = *(const v8h*)&bufB[(wn + 16 * (NF / 2 + j) + rl) * 32 + fc];
        if (t + 3 < NT) stageB(t + 3, (t + 3) & 3);
        lgkm0();
        __builtin_amdgcn_s_setprio(1);
#pragma unroll
        for (int i = 0; i < MF; ++i)
#pragma unroll
            for (int j = 0; j < NF / 2; ++j)
                acc[i][NF / 2 + j] = __builtin_amdgcn_mfma_f32_16x16x32_f16(af[i], bg[j], acc[i][NF / 2 + j], 0, 0, 0);
        __builtin_amdgcn_s_setprio(0);
        // no barrier here: loop-top vmcnt+barrier provides the ordering
    }

    // epilogue
#pragma unroll
    for (int i = 0; i < MF; ++i)
#pragma unroll
        for (int j = 0; j < NF; ++j) {
            const int col = bn + wn + 16 * j + rl;
            const int row0 = bm + wm + 16 * i + quad * 4;
#pragma unroll
            for (int r = 0; r < 4; ++r)
                C[(size_t)(row0 + r) * ldc + col] = acc[i][j][r] * outScale;
        }
}

// ---------------------------------------------------------------------------
// Gate GEMV (fp32, exact): qkv[m][4096+g] = hidden[m] . w_qkv[2048+g]
// ---------------------------------------------------------------------------
__global__ __launch_bounds__(256) void gate_kernel(const float* __restrict__ hidden,
                                                   const float* __restrict__ w_qkv,
                                                   float* __restrict__ qkv)
{
    const int lane = threadIdx.x & 63, wv = threadIdx.x >> 6;
    const int m = blockIdx.x * 4 + wv;
    const float* hp = hidden + (size_t)m * cK;
    float4 h4[8];
#pragma unroll
    for (int i = 0; i < 8; ++i) h4[i] = *(const float4*)&hp[i * 256 + lane * 4];
#pragma unroll 1
    for (int g = 0; g < 16; ++g) {
        const float* wp = w_qkv + (size_t)(cHID + g) * cK;
        float acc = 0.f;
#pragma unroll
        for (int i = 0; i < 8; ++i) {
            float4 w4 = *(const float4*)&wp[i * 256 + lane * 4];
            acc = fmaf(h4[i].x, w4.x, acc);
            acc = fmaf(h4[i].y, w4.y, acc);
            acc = fmaf(h4[i].z, w4.z, acc);
            acc = fmaf(h4[i].w, w4.w, acc);
        }
#pragma unroll
        for (int k = 1; k < 64; k <<= 1) acc += __shfl_xor(acc, k);
        if (lane == 0) qkv[(size_t)m * cQKV + cGO2 + g] = acc;
    }
}

// ---------------------------------------------------------------------------
// In-place RoPE on q and k regions of qkv (M, 4112). K at 2048.
// ---------------------------------------------------------------------------
__global__ __launch_bounds__(256) void rope_kernel(float* __restrict__ qkv,
                                                   const float* __restrict__ cosp,
                                                   const float* __restrict__ sinp)
{
    int idx = blockIdx.x * 256 + threadIdx.x;
    const int qcount = cM * cNH * (cHD / 2);
    int d, m;
    size_t base;
    if (idx < qcount) {
        d = idx & 63;
        int t = idx >> 6;
        int head = t & (cNH - 1);
        m = t >> 4;
        base = (size_t)m * cQKV + head * cHD;
    } else {
        int loc = idx - qcount;
        d = loc & 63;
        int t = loc >> 6;
        int head = t & (cNKV - 1);
        m = t >> 3;
        base = (size_t)m * cQKV + cKO2 + head * cHD;
    }
    int s = m & (cS - 1);
    float x1 = qkv[base + d], x2 = qkv[base + d + 64];
    float c1 = cosp[s * cHD + d], c2 = cosp[s * cHD + d + 64];
    float s1 = sinp[s * cHD + d], s2 = sinp[s * cHD + d + 64];
    qkv[base + d]      = x1 * c1 - x2 * s1;
    qkv[base + d + 64] = x2 * c2 + x1 * s2;
}

// ---------------------------------------------------------------------------
// Roped K -> planar fp16 (hi only): Kh[b][kvh][s][128]
// ---------------------------------------------------------------------------
__global__ __launch_bounds__(256) void split_k_kernel(const float* __restrict__ qkv,
                                                      unsigned short* __restrict__ Kh)
{
    int idx = blockIdx.x * 256 + threadIdx.x;     // 2^20 float4 groups
    int d4 = idx & 31;
    int s  = (idx >> 5) & 2047;
    int kv = (idx >> 16) & 7;
    int b  = idx >> 19;
    const float4 v = *(const float4*)&qkv[(size_t)(b * cS + s) * cQKV + cKO2 + kv * cHD + d4 * 4];
    size_t o = ((size_t)((b * cNKV + kv) * cS + s)) * cHD + d4 * 4;
    *(ushort4*)&Kh[o] = make_ushort4(f2h(v.x), f2h(v.y), f2h(v.z), f2h(v.w));
}

// ---------------------------------------------------------------------------
// V, transposed, fp16 hi only: Vh[b][kvh][d][s]
// ---------------------------------------------------------------------------
__global__ __launch_bounds__(256) void split_vt_kernel(const float* __restrict__ qkv,
                                                       unsigned short* __restrict__ Vh)
{
    __shared__ float T[128 * 132];
    const int t = threadIdx.x;
    const int tile = blockIdx.x, kv = blockIdx.y, b = blockIdx.z;
#pragma unroll
    for (int i = 0; i < 16; ++i) {
        int e = i * 256 + t;
        int row = e >> 5, c4 = e & 31;
        *(float4*)&T[row * 132 + c4 * 4] =
            *(const float4*)&qkv[(size_t)(b * cS + tile * 128 + row) * cQKV + cVO2 + kv * cHD + c4 * 4];
    }
    __syncthreads();
    const int d = t >> 1, half = t & 1;
    size_t ob = ((size_t)((b * cNKV + kv) * cHD + d)) * cS + tile * 128 + half * 64;
#pragma unroll
    for (int i = 0; i < 8; ++i) {
        unsigned short hh[8];
#pragma unroll
        for (int j = 0; j < 8; ++j)
            hh[j] = f2h(T[(half * 64 + i * 8 + j) * 132 + d]);
        *(ushort4*)&Vh[ob + i * 8]     = make_ushort4(hh[0], hh[1], hh[2], hh[3]);
        *(ushort4*)&Vh[ob + i * 8 + 4] = make_ushort4(hh[4], hh[5], hh[6], hh[7]);
    }
}

// ---------------------------------------------------------------------------
// MFMA flash attention + gate, S^T formulation, fp16, FIXED-OFFSET softmax.
// NEW: counted-vmcnt deep pipeline -- 4 K/V LDS buffers (64KB), prefetch
// depth 3, ONE barrier per iteration at loop top preceded by vmcnt(8)
// (retires exactly tile kt's 4 loads; kt+1, kt+2 stay in flight across the
// barrier; never drained to 0 in the loop). lgkmcnt(0)+sched_barrier fences
// before each MFMA cluster (rule #18), setprio(1) around clusters (T5).
// Race-freedom: stage(kt+3) writes buffer (kt-1)&3, whose reads completed
// before this iteration's top barrier.
// ---------------------------------------------------------------------------
__global__ __launch_bounds__(256, 2) void attn_mfma(const float* __restrict__ qkv,
                                                    const unsigned short* __restrict__ Kh,
                                                    const unsigned short* __restrict__ Vh,
                                                    unsigned short* __restrict__ Oh,
                                                    unsigned short* __restrict__ Ol)
{
    __shared__ __align__(16) unsigned short sKh[4 * 4096];
    __shared__ __align__(16) unsigned short sVh[4 * 4096];

    const int tid = threadIdx.x;
    const int lane = tid & 63, w = tid >> 6;
    const int rl = lane & 15, quad = lane >> 4;
    const int qt = blockIdx.x, h = blockIdx.y, b = blockIdx.z;
    const int kvh = h >> 1;
    const float sc = 0.08838834764831845f * 1.4426950408889634f;  // /sqrt(128)*log2e

    // ---- Q fragments, fp16 hi/lo, unscaled ----
    v8h Qh[2][4], Ql[2][4];
#pragma unroll
    for (int mt = 0; mt < 2; ++mt) {
        const float* qp0 = &qkv[(size_t)(b * cS + qt * 128 + w * 32 + mt * 16 + rl) * cQKV
                                + h * cHD + quad * 8];
#pragma unroll
        for (int c = 0; c < 4; ++c) {
            float4 x0 = *(const float4*)(qp0 + c * 32);
            float4 x1 = *(const float4*)(qp0 + c * 32 + 4);
            float f[8] = {x0.x, x0.y, x0.z, x0.w, x1.x, x1.y, x1.z, x1.w};
            v8s qh, ql;
#pragma unroll
            for (int j = 0; j < 8; ++j) {
                unsigned short hh, ll;
                split2h(f[j], hh, ll);
                qh[j] = (short)hh; ql[j] = (short)ll;
            }
            Qh[mt][c] = __builtin_bit_cast(v8h, qh);
            Ql[mt][c] = __builtin_bit_cast(v8h, ql);
        }
    }

    float l_i[2] = {0.f, 0.f};     // per-lane partial (this quad's k-rows)
    v4f O[2][8];   // O^T: [mt][dt], row d = dt*16+quad*4+r, col q = rl
#pragma unroll
    for (int mt = 0; mt < 2; ++mt)
#pragma unroll
        for (int dt = 0; dt < 8; ++dt) O[mt][dt] = (v4f){0.f, 0.f, 0.f, 0.f};

    const size_t kbase = ((size_t)((b * cNKV + kvh) * cS)) * cHD;
    const size_t vbase = ((size_t)((b * cNKV + kvh) * cHD)) * cS;

    // ---- staging pointers (GLD16: wave-uniform LDS base + lane*16B) ----
    const int kchunk = 4 * w + (lane >> 5);          // +2 for second inst
    const int krow = lane & 31;
    const unsigned short* gKh0 = Kh + kbase + (size_t)krow * cHD + kchunk * 8;
    const unsigned short* gVh0 = Vh + vbase + (size_t)lane * cS + w * 8;
    unsigned short* dKh0 = sKh + w * 1024;
    unsigned short* dVh0 = sVh + w * 1024;

#define STAGEK(kt_, buf_)                                                        \
    do {                                                                         \
        const size_t ko_ = (size_t)(kt_) * (32 * cHD);                           \
        const int bo_ = (buf_) * 4096;                                           \
        GLD16(gKh0 + ko_, dKh0 + bo_); GLD16(gKh0 + ko_ + 16, dKh0 + bo_ + 512); \
    } while (0)
#define STAGEV(kt_, buf_)                                                        \
    do {                                                                         \
        const size_t vo_ = (size_t)(kt_) * 32;                                   \
        const int bo_ = (buf_) * 4096;                                           \
        GLD16(gVh0 + vo_, dVh0 + bo_);                                           \
        GLD16(gVh0 + vo_ + 64 * (size_t)cS, dVh0 + bo_ + 512);                   \
    } while (0)

    // prologue: 3 tiles in flight, per-tile order K then V (4 loads/tile)
    STAGEK(0, 0); STAGEV(0, 0);
    STAGEK(1, 1); STAGEV(1, 1);
    STAGEK(2, 2); STAGEV(2, 2);

    constexpr int NT = cS / 32;   // 64
    for (int kt = 0; kt < NT; ++kt) {
        // counted wait: retire exactly tile kt's 4 loads; kt+1,kt+2 in flight
        if (kt < NT - 2)       vmwait<8>();
        else if (kt == NT - 2) vmwait<4>();
        else                   vmwait<0>();
        barrier_();                               // tile kt globally visible

        const int cbo = (kt & 3) * 4096;

        // (1) K fragments LDS -> registers; stage K of kt+3 behind them
        v8h kf[4][2];
#pragma unroll
        for (int c = 0; c < 4; ++c)
#pragma unroll
            for (int nt = 0; nt < 2; ++nt)
                kf[c][nt] = *(const v8h*)&sKh[cbo + ((4 * c + quad) * 32 + nt * 16 + rl) * 8];
        if (kt + 3 < NT) STAGEK(kt + 3, (kt + 3) & 3);
        lgkm0();

        // (2) S^T = K @ Q^T  (fp16 2-pass)
        v4f S[2][2];
#pragma unroll
        for (int mt = 0; mt < 2; ++mt)
#pragma unroll
            for (int nt = 0; nt < 2; ++nt) S[mt][nt] = (v4f){0.f, 0.f, 0.f, 0.f};
        __builtin_amdgcn_s_setprio(1);
#pragma unroll
        for (int c = 0; c < 4; ++c)
#pragma unroll
            for (int nt = 0; nt < 2; ++nt)
#pragma unroll
                for (int mt = 0; mt < 2; ++mt) {
                    S[mt][nt] = __builtin_amdgcn_mfma_f32_16x16x32_f16(kf[c][nt], Qh[mt][c], S[mt][nt], 0, 0, 0);
                    S[mt][nt] = __builtin_amdgcn_mfma_f32_16x16x32_f16(kf[c][nt], Ql[mt][c], S[mt][nt], 0, 0, 0);
                }
        __builtin_amdgcn_s_setprio(0);

        // (3) fixed-offset softmax: p = exp2(S*sc - 10); l partial accum;
        //     P^T fp16 B-frag via cvt_pkrtz + one shfl per jj
        v8h PhB[2];
#pragma unroll
        for (int mt = 0; mt < 2; ++mt) {
            float p[8];
#pragma unroll
            for (int nt = 0; nt < 2; ++nt)
#pragma unroll
                for (int r = 0; r < 4; ++r) {
                    float e = exp2f(fmaf(S[mt][nt][r], sc, -10.f));
                    p[nt * 4 + r] = e;
                    l_i[mt] += e;
                }
            // pk[r]: hi16 = h(p_nt0[r]), lo16 = h(p_nt1[r])
            int pk[4];
#pragma unroll
            for (int r = 0; r < 4; ++r)
                pk[r] = __builtin_bit_cast(int,
                        __builtin_amdgcn_cvt_pkrtz(p[4 + r], p[r]));
            // transpose C-layout -> B-frag (one shfl per jj)
            const int q2 = (quad & 1) * 2;
            const int hiHalf = quad >> 1;       // 0: nt0 (hi16), 1: nt1 (lo16)
            v8s ph;
#pragma unroll
            for (int jj = 0; jj < 8; ++jj) {
                int srcl = (q2 + (jj >> 2)) * 16 + rl;
                int v = __shfl(pk[jj & 3], srcl);
                ph[jj] = hiHalf ? (short)(v & 0xffff) : (short)(((unsigned)v) >> 16);
            }
            PhB[mt] = __builtin_bit_cast(v8h, ph);
        }

        // (4) V fragments LDS -> registers; stage V of kt+3 behind them
        v8h vf[8];
#pragma unroll
        for (int dt = 0; dt < 8; ++dt)
            vf[dt] = *(const v8h*)&sVh[cbo + (quad * 128 + dt * 16 + rl) * 8];
        if (kt + 3 < NT) STAGEV(kt + 3, (kt + 3) & 3);
        lgkm0();

        // (5) O^T += V^T @ P^T  (fp16 1-pass)
        __builtin_amdgcn_s_setprio(1);
#pragma unroll
        for (int dt = 0; dt < 8; ++dt)
#pragma unroll
            for (int mt = 0; mt < 2; ++mt)
                O[mt][dt] = __builtin_amdgcn_mfma_f32_16x16x32_f16(vf[dt], PhB[mt], O[mt][dt], 0, 0, 0);
        __builtin_amdgcn_s_setprio(0);
        // no trailing barrier: loop-top vmcnt+barrier provides the ordering
    }
#undef STAGEK
#undef STAGEV

    // ---- epilogue: reduce l across quads, x16/l, sigmoid gate, store ----
#pragma unroll
    for (int mt = 0; mt < 2; ++mt) {
        float lt = l_i[mt];
        lt += __shfl_xor(lt, 16);
        lt += __shfl_xor(lt, 32);
        int grow = b * cS + qt * 128 + w * 32 + mt * 16 + rl;
        float g = qkv[(size_t)grow * cQKV + cGO2 + h];
        float u = 16.f / ((1.f + __expf(-g)) * lt);
        size_t obase = (size_t)grow * cHID + h * cHD + quad * 4;
#pragma unroll
        for (int dt = 0; dt < 8; ++dt) {
            unsigned short hh[4], ll[4];
#pragma unroll
            for (int r = 0; r < 4; ++r) split2h(O[mt][dt][r] * u, hh[r], ll[r]);
            *(ushort4*)&Oh[obase + dt * 16] = make_ushort4(hh[0], hh[1], hh[2], hh[3]);
            *(ushort4*)&Ol[obase + dt * 16] = make_ushort4(ll[0], ll[1], ll[2], ll[3]);
        }
    }
}

// ---------------------------------------------------------------------------
extern "C" void kernel_launch(void* const* d_in, const int* in_sizes, int n_in,
                              void* d_out, int out_size, void* d_ws, size_t ws_size,
                              hipStream_t stream)
{
    (void)in_sizes; (void)n_in; (void)out_size; (void)ws_size;
    const float* hidden = (const float*)d_in[0];
    const float* cosp   = (const float*)d_in[1];
    const float* sinp   = (const float*)d_in[2];
    const float* w_qkv  = (const float*)d_in[3];
    const float* w_o    = (const float*)d_in[4];
    float* out = (float*)d_out;

    // Workspace layout (bytes):
    //  [0, 67371008)              qkv f32 [4096][4112] (REORDERED: Q|K|V|gate)
    //  [67371008, 101974016)      Bh (w_qkv hi) -> reused as Oh/Ol
    //  [101974016, 118751232)     Kh + Vh -> later Wh (w_o hi)
    // d_out doubles as Ah/Al (hidden split) until GEMM2 writes it.
    char* ws = (char*)d_ws;
    float* qkv = (float*)ws;
    unsigned short* Bh = (unsigned short*)(ws + 67371008);
    unsigned short* Kh = (unsigned short*)(ws + 101974016);
    const size_t kvPlane = (size_t)cB * cNKV * cS * cHD;       // 4,194,304 elems
    unsigned short* Vh = Kh + kvPlane;

    unsigned short* Ahid = (unsigned short*)d_out;             // hidden split hi
    unsigned short* Alid = Ahid + (size_t)cM * cK;             // hidden split lo
    unsigned short* Oh = Bh;                                   // attn out hi
    unsigned short* Ol = Bh + (size_t)cM * cHID;               // attn out lo
    unsigned short* Wh = Kh;                                   // w_o hi

    // 1) split inputs to fp16
    split_mat2<<<dim3(cM * (cK / 4) / 256), 256, 0, stream>>>(hidden, Ahid, Alid, cM);
    split_maqkv<<<dim3(4096 * (cK / 4) / 256), 256, 0, stream>>>(w_qkv, Bh);

    // 2) QKV projection (Q|K|V, 4096 cols), grid 256 = 1 block/CU zero-tail
    gemm8p<8, 4><<<dim3(256), 512, 0, stream>>>(Ahid, Alid, Bh, qkv, cQKV, 1.0f, 16);

    // 2b) gate columns (16) in exact fp32
    gate_kernel<<<dim3(cM / 4), 256, 0, stream>>>(hidden, w_qkv, qkv);

    // 3) RoPE in place
    {
        int total = cM * cNH * (cHD / 2) + cM * cNKV * (cHD / 2);
        rope_kernel<<<dim3(total / 256), 256, 0, stream>>>(qkv, cosp, sinp);
    }

    // 4) K (planar) and V (transposed) to fp16 hi
    split_k_kernel<<<dim3(4096), 256, 0, stream>>>(qkv, Kh);
    split_vt_kernel<<<dim3(cS / 128, cNKV, cB), 256, 0, stream>>>(qkv, Vh);

    // 5) MFMA attention + gate -> Oh/Ol (overwrites dead w_qkv split)
    attn_mfma<<<dim3(cS / 128, cNH, cB), 256, 0, stream>>>(qkv, Kh, Vh, Oh, Ol);

    // 6) w_o hi (overwrites dead K plane)
    split_math<<<dim3(cHID * (cK / 4) / 256), 256, 0, stream>>>(w_o, Wh, cHID);

    // 7) output projection: BN=128 variant, grid 256 (zero tail)
    gemm8p<4, 4><<<dim3(256), 512, 0, stream>>>(Oh, Ol, Wh, out, cHID, 1.0f / 16.0f, 16);
}